// Round 1
// baseline (146.273 us; speedup 1.0000x reference)
//
#include <hip/hip_runtime.h>

// SRHT: out[row, j] = h[row, perm[j]],  h = chain of 3 x (rad-mult + FWHT1024) per 4 blocks.
// One workgroup (256 thr = 4 waves) per row; wave w handles block w.
// Each lane holds 16 f32. FWHT bits 0-7 via register stages + 3 LDS layout exchanges;
// bits 8,9 via permlane16/32_swap (VALU pipe). LDS is XOR-swizzled (chi) for bank spread.

typedef unsigned uintv2 __attribute__((ext_vector_type(2)));

__device__ __forceinline__ float partner16(float x, int lane) {
#if __has_builtin(__builtin_amdgcn_permlane16_swap)
  unsigned u = __float_as_uint(x);
  uintv2 r = __builtin_amdgcn_permlane16_swap(u, u, false, false);
  return __uint_as_float((lane & 16) ? r[0] : r[1]);
#else
  return __shfl_xor(x, 16, 64);
#endif
}

__device__ __forceinline__ float partner32(float x, int lane) {
#if __has_builtin(__builtin_amdgcn_permlane32_swap)
  unsigned u = __float_as_uint(x);
  uintv2 r = __builtin_amdgcn_permlane32_swap(u, u, false, false);
  return __uint_as_float((lane & 32) ? r[0] : r[1]);
#else
  return __shfl_xor(x, 32, 64);
#endif
}

// 16-point FWHT over the 4 register-held index bits (any layout).
__device__ __forceinline__ void fwht16(float v[16]) {
#pragma unroll
  for (int h = 1; h < 16; h <<= 1) {
#pragma unroll
    for (int r = 0; r < 16; r++) {
      if (!(r & h)) {
        float a = v[r], b = v[r ^ h];
        v[r] = a + b;
        v[r ^ h] = a - b;
      }
    }
  }
}

// Butterflies on index bits 8,9 (lane bits 4,5): new = partner + s*mine.
__device__ __forceinline__ void laneStages89(float v[16], int lane, float s16, float s32) {
#pragma unroll
  for (int r = 0; r < 16; r++) v[r] = fmaf(s16, v[r], partner16(v[r], lane));
#pragma unroll
  for (int r = 0; r < 16; r++) v[r] = fmaf(s32, v[r], partner32(v[r], lane));
}

// Exchange register-held nibble with the lane-low nibble through the wave's private
// 1024-word LDS region. Physical word = chi(256*a + 16*hi + lo) with
// chi(w) = w ^ (((w>>8)&3)<<3)  (flips bit3 by a0, bit4 by a1).
// Writes: strided b32 (2-way banks = free). Reads: 4 x b128, chunk-permuted (uniform).
__device__ __forceinline__ void exchangeWave(float v[16], float* reg, int lane) {
  const int a  = lane >> 4;
  const int m  = lane & 15;
  const int a0 = a & 1;
  const int a1 = a >> 1;
  float* wptr = reg + (a << 8) + (m ^ (a0 << 3));
  __builtin_amdgcn_wave_barrier();
#pragma unroll
  for (int r = 0; r < 16; r++)
    wptr[(r ^ a1) << 4] = v[r];
  __builtin_amdgcn_wave_barrier();
  const float4* rptr = (const float4*)(reg + (a << 8) + ((m ^ a1) << 4));
#pragma unroll
  for (int k = 0; k < 4; k++) {
    float4 q = rptr[k ^ (a0 << 1)];
    v[4 * k + 0] = q.x; v[4 * k + 1] = q.y;
    v[4 * k + 2] = q.z; v[4 * k + 3] = q.w;
  }
  __builtin_amdgcn_wave_barrier();
}

__global__ __launch_bounds__(256) void srht_kernel(
    const float* __restrict__ x, const float* __restrict__ rad,
    const int* __restrict__ perm, float* __restrict__ out) {
  __shared__ __align__(16) float lds[4096];
  const int row  = blockIdx.x;
  const int tid  = threadIdx.x;
  const int w    = tid >> 6;   // FWHT block b
  const int lane = tid & 63;

  const float s16 = (lane & 16) ? -1.f : 1.f;
  const float s32 = (lane & 32) ? -1.f : 1.f;
  float* reg = lds + (w << 10);

  // ---- load x (layout LA: i = lane*16 + r) and multiply rad0 ----
  float v[16];
  {
    const float4* xp  = (const float4*)(x + (size_t)row * 1024 + (lane << 4));
    const float4* r0p = (const float4*)(rad + (w << 10) + (lane << 4));
#pragma unroll
    for (int q = 0; q < 4; q++) {
      float4 xv = xp[q];
      float4 rv = r0p[q];
      v[4 * q + 0] = xv.x * rv.x;
      v[4 * q + 1] = xv.y * rv.y;
      v[4 * q + 2] = xv.z * rv.z;
      v[4 * q + 3] = xv.w * rv.w;
    }
  }

  // ---- FWHT #1 ----
  fwht16(v);                       // bits 0-3 (LA)
  exchangeWave(v, reg, lane);      // LA -> LB
  fwht16(v);                       // bits 4-7 (LB)
  laneStages89(v, lane, s16, s32); // bits 8,9

  // ---- (1/32) * rad1, LB addressing: i = 256*(lane>>4) + 16*r + (lane&15) ----
  {
    const float* r1 = rad + 4096 + (w << 10) + ((lane >> 4) << 8) + (lane & 15);
#pragma unroll
    for (int r = 0; r < 16; r++)
      v[r] *= 0.03125f * r1[r << 4];
  }

  // ---- FWHT #2 ----
  fwht16(v);                       // bits 4-7 (LB)
  laneStages89(v, lane, s16, s32); // bits 8,9
  exchangeWave(v, reg, lane);      // LB -> LA
  fwht16(v);                       // bits 0-3 (LA)

  // ---- (1/32) * rad2, LA addressing (contiguous) ----
  {
    const float4* r2p = (const float4*)(rad + 8192 + (w << 10) + (lane << 4));
#pragma unroll
    for (int q = 0; q < 4; q++) {
      float4 rv = r2p[q];
      v[4 * q + 0] *= 0.03125f * rv.x;
      v[4 * q + 1] *= 0.03125f * rv.y;
      v[4 * q + 2] *= 0.03125f * rv.z;
      v[4 * q + 3] *= 0.03125f * rv.w;
    }
  }

  // ---- FWHT #3 ----
  fwht16(v);                       // bits 0-3 (LA)
  exchangeWave(v, reg, lane);      // LA -> LB
  fwht16(v);                       // bits 4-7 (LB)
  laneStages89(v, lane, s16, s32); // bits 8,9

  // ---- store h into true-index LDS (chi-swizzled), own region ----
  {
    const int a = lane >> 4, m = lane & 15, a0 = a & 1, a1 = a >> 1;
    float* hp = reg + (a << 8) + (m ^ (a0 << 3));
    __builtin_amdgcn_wave_barrier();
#pragma unroll
    for (int r = 0; r < 16; r++)
      hp[(r ^ a1) << 4] = v[r];
  }
  __syncthreads();

  // ---- permutation gather: out[row, j] = h[perm[j]] ----
  {
    const int4* pp = (const int4*)(perm + (tid << 4));
    float4* op = (float4*)(out + (size_t)row * 4096 + (tid << 4));
#pragma unroll
    for (int g = 0; g < 4; g++) {
      int4 pi = pp[g];
      float4 o;
      int p0 = pi.x; o.x = lds[p0 ^ (((p0 >> 8) & 3) << 3)];
      int p1 = pi.y; o.y = lds[p1 ^ (((p1 >> 8) & 3) << 3)];
      int p2 = pi.z; o.z = lds[p2 ^ (((p2 >> 8) & 3) << 3)];
      int p3 = pi.w; o.w = lds[p3 ^ (((p3 >> 8) & 3) << 3)];
      op[g] = o;
    }
  }
}

extern "C" void kernel_launch(void* const* d_in, const int* in_sizes, int n_in,
                              void* d_out, int out_size, void* d_ws, size_t ws_size,
                              hipStream_t stream) {
  (void)n_in; (void)d_ws; (void)ws_size; (void)out_size;
  const float* x    = (const float*)d_in[0];
  const float* rad  = (const float*)d_in[1];
  const int*   perm = (const int*)d_in[2];
  float*       out  = (float*)d_out;
  const int rows = in_sizes[0] / 1024;  // 16384
  srht_kernel<<<rows, 256, 0, stream>>>(x, rad, perm, out);
}

// Round 2
// 138.238 us; speedup vs baseline: 1.0581x; 1.0581x over previous
//
#include <hip/hip_runtime.h>

// SRHT via MFMA: FWHT1024 = H32 (x) H32 on a 32x32 matrix view.
// Chain of 6 products M <- (H32*M)^T using mfma_f32_32x32x16_f16; the MFMA
// C-layout (col=lane&31, rows in regs) reinterpreted as the next A operand is
// exactly M^T, so chaining costs only 8 cvt_pk_rtz + 4 permlane32_swap per
// product. H32 built in-register from popc(k&n); 1/32 folded into B' = H/32.
// LDS used only for the final permutation gather.

typedef float f32x16 __attribute__((ext_vector_type(16)));
typedef __fp16 f16x8 __attribute__((ext_vector_type(8)));
typedef unsigned int uintv2 __attribute__((ext_vector_type(2)));

union H8U4 { f16x8 h; unsigned int u[4]; };

__device__ __forceinline__ unsigned int pkrtz(float a, float b) {
  auto p = __builtin_amdgcn_cvt_pkrtz(a, b);   // lo = f16(a), hi = f16(b)
  return __builtin_bit_cast(unsigned int, p);
}

__device__ __forceinline__ f32x16 prod(const f16x8& A0, const f16x8& A1,
                                       const f16x8& B0, const f16x8& B1) {
  f32x16 z = {0.f,0.f,0.f,0.f, 0.f,0.f,0.f,0.f, 0.f,0.f,0.f,0.f, 0.f,0.f,0.f,0.f};
  z = __builtin_amdgcn_mfma_f32_32x32x16_f16(A0, B0, z, 0, 0, 0);
  z = __builtin_amdgcn_mfma_f32_32x32x16_f16(A1, B1, z, 0, 0, 0);
  return z;
}

// C (f32x16, col=lane&31, row=(j&3)+8*(j>>2)+4*hi) -> A fragments of C^T.
// A[row=lane&31][k=16t+8*hi+jj]: lane needs C rows 16t+8*hi+jj at its own col.
// Pack row-pairs to f16 words W0..W7; permlane32_swap(Wa,Wb) delivers
// (own lo-half word, partner word) exactly where each half-wave needs them.
__device__ __forceinline__ void convA(const f32x16& c, f16x8& A0, f16x8& A1) {
  unsigned int W[8];
#pragma unroll
  for (int m = 0; m < 8; m++) W[m] = pkrtz(c[2 * m], c[2 * m + 1]);
  H8U4 a0, a1;
  uintv2 r;
  r = __builtin_amdgcn_permlane32_swap(W[0], W[2], false, false); a0.u[0] = r[0]; a0.u[2] = r[1];
  r = __builtin_amdgcn_permlane32_swap(W[1], W[3], false, false); a0.u[1] = r[0]; a0.u[3] = r[1];
  r = __builtin_amdgcn_permlane32_swap(W[4], W[6], false, false); a1.u[0] = r[0]; a1.u[2] = r[1];
  r = __builtin_amdgcn_permlane32_swap(W[5], W[7], false, false); a1.u[1] = r[0]; a1.u[3] = r[1];
  A0 = a0.h; A1 = a1.h;
}

__global__ __launch_bounds__(256) void srht_kernel(
    const float* __restrict__ x, const float* __restrict__ rad,
    const int* __restrict__ perm, float* __restrict__ out) {
  __shared__ __align__(16) float lds[4096];
  const int row  = blockIdx.x;
  const int tid  = threadIdx.x;
  const int w    = tid >> 6;        // FWHT block
  const int lane = tid & 63;
  const int q    = lane & 31;       // matrix column owned by this lane
  const int hi   = lane >> 5;

  // ---- H32 B-fragments: B[k][n=q], k = 16t + 8*hi + jj. Bs = H/32. ----
  f16x8 B0, B1, Bs0, Bs1;
  {
    H8U4 b0, b1, bs0, bs1;
#pragma unroll
    for (int t = 0; t < 2; t++) {
#pragma unroll
      for (int m = 0; m < 4; m++) {
        int k0 = 16 * t + 8 * hi + 2 * m;
        unsigned int s0 = (unsigned)(__popc(k0 & q) & 1);
        unsigned int s1 = (unsigned)(__popc((k0 + 1) & q) & 1);
        unsigned int sm = (s0 << 15) | (s1 << 31);
        unsigned int w1 = 0x3C003C00u ^ sm;   // +-1.0 f16
        unsigned int ws = 0x28002800u ^ sm;   // +-2^-5 f16
        if (t == 0) { b0.u[m] = w1; bs0.u[m] = ws; }
        else        { b1.u[m] = w1; bs1.u[m] = ws; }
      }
    }
    B0 = b0.h; B1 = b1.h; Bs0 = bs0.h; Bs1 = bs1.h;
  }

  // ---- first A = (x*rad0)^T : lane loads x[32k + q], k = 16t+8hi+jj ----
  f16x8 A0, A1;
  {
    const float* xp  = x + (size_t)row * 1024 + q;
    const float* r0p = rad + (w << 10) + q;
    H8U4 a0, a1;
#pragma unroll
    for (int t = 0; t < 2; t++) {
#pragma unroll
      for (int m = 0; m < 4; m++) {
        int k0 = ((t << 4) + (hi << 3) + (m << 1)) << 5;
        int k1 = k0 + 32;
        float v0 = xp[k0] * r0p[k0];
        float v1 = xp[k1] * r0p[k1];
        unsigned int wd = pkrtz(v0, v1);
        if (t == 0) a0.u[m] = wd; else a1.u[m] = wd;
      }
    }
    A0 = a0.h; A1 = a1.h;
  }

  f32x16 c;
  c = prod(A0, A1, B0, B1);                    // C1 = X^T H
  convA(c, A0, A1);
  c = prod(A0, A1, B0, B1);                    // C2 = H X H  (fwht #1)

  // ---- * rad1 (1/32 folded into Bs of next product) ----
  {
    const float* r1p = rad + ((4 + w) << 10) + q;
#pragma unroll
    for (int j = 0; j < 16; j++) {
      int p = (j & 3) + ((j >> 2) << 3) + (hi << 2);
      c[j] *= r1p[p << 5];
    }
  }
  convA(c, A0, A1);
  c = prod(A0, A1, Bs0, Bs1);                  // C3 (carries 1/32)
  convA(c, A0, A1);
  c = prod(A0, A1, B0, B1);                    // C4 = fwht #2 / 32

  // ---- * rad2 ----
  {
    const float* r2p = rad + ((8 + w) << 10) + q;
#pragma unroll
    for (int j = 0; j < 16; j++) {
      int p = (j & 3) + ((j >> 2) << 3) + (hi << 2);
      c[j] *= r2p[p << 5];
    }
  }
  convA(c, A0, A1);
  c = prod(A0, A1, Bs0, Bs1);                  // C5 (carries 1/32)
  convA(c, A0, A1);
  c = prod(A0, A1, B0, B1);                    // C6 = final h, i = 32p + q

  // ---- h -> LDS at true index (writes are 2-way/bank = free) ----
#pragma unroll
  for (int j = 0; j < 16; j++) {
    int p = (j & 3) + ((j >> 2) << 3) + (hi << 2);
    lds[(w << 10) + (p << 5) + q] = c[j];
  }
  __syncthreads();

  // ---- permutation gather, coalesced float4 stores ----
  {
    const int4* pp = (const int4*)(perm + (tid << 4));
    float4* op = (float4*)(out + (size_t)row * 4096 + (tid << 4));
#pragma unroll
    for (int g = 0; g < 4; g++) {
      int4 pi = pp[g];
      float4 o;
      o.x = lds[pi.x];
      o.y = lds[pi.y];
      o.z = lds[pi.z];
      o.w = lds[pi.w];
      op[g] = o;
    }
  }
}

extern "C" void kernel_launch(void* const* d_in, const int* in_sizes, int n_in,
                              void* d_out, int out_size, void* d_ws, size_t ws_size,
                              hipStream_t stream) {
  (void)n_in; (void)d_ws; (void)ws_size; (void)out_size;
  const float* x    = (const float*)d_in[0];
  const float* rad  = (const float*)d_in[1];
  const int*   perm = (const int*)d_in[2];
  float*       out  = (float*)d_out;
  const int rows = in_sizes[0] / 1024;  // 16384
  srht_kernel<<<rows, 256, 0, stream>>>(x, rad, perm, out);
}

// Round 3
// 120.136 us; speedup vs baseline: 1.2176x; 1.1507x over previous
//
#include <hip/hip_runtime.h>

// SRHT via MFMA: FWHT1024 = H32 (x) H32 on a 32x32 matrix view.
// Chain of 6 products M <- (H32*M)^T using mfma_f32_32x32x16_f16; the MFMA
// C-layout (col=lane&31, rows in regs) reinterpreted as the next A operand is
// exactly M^T, so chaining costs only 8 cvt_pk_rtz + 4 permlane32_swap per
// product. H32 built in-register from popc(k&n); 1/32 folded into B' = H/32.
// LDS used only for the final permutation gather.
// R2 fix: gather/store indexed j = g*1024 + tid*4 so each store instruction is
// 64 lanes x 16B CONTIGUOUS (1KB/wave) instead of 16B-at-64B-stride (4x the
// L2 write transactions -> was capping the kernel at ~2.2 TB/s).

typedef float f32x16 __attribute__((ext_vector_type(16)));
typedef __fp16 f16x8 __attribute__((ext_vector_type(8)));
typedef unsigned int uintv2 __attribute__((ext_vector_type(2)));

union H8U4 { f16x8 h; unsigned int u[4]; };

__device__ __forceinline__ unsigned int pkrtz(float a, float b) {
  auto p = __builtin_amdgcn_cvt_pkrtz(a, b);   // lo = f16(a), hi = f16(b)
  return __builtin_bit_cast(unsigned int, p);
}

__device__ __forceinline__ f32x16 prod(const f16x8& A0, const f16x8& A1,
                                       const f16x8& B0, const f16x8& B1) {
  f32x16 z = {0.f,0.f,0.f,0.f, 0.f,0.f,0.f,0.f, 0.f,0.f,0.f,0.f, 0.f,0.f,0.f,0.f};
  z = __builtin_amdgcn_mfma_f32_32x32x16_f16(A0, B0, z, 0, 0, 0);
  z = __builtin_amdgcn_mfma_f32_32x32x16_f16(A1, B1, z, 0, 0, 0);
  return z;
}

// C (f32x16, col=lane&31, row=(j&3)+8*(j>>2)+4*hi) -> A fragments of C^T.
__device__ __forceinline__ void convA(const f32x16& c, f16x8& A0, f16x8& A1) {
  unsigned int W[8];
#pragma unroll
  for (int m = 0; m < 8; m++) W[m] = pkrtz(c[2 * m], c[2 * m + 1]);
  H8U4 a0, a1;
  uintv2 r;
  r = __builtin_amdgcn_permlane32_swap(W[0], W[2], false, false); a0.u[0] = r[0]; a0.u[2] = r[1];
  r = __builtin_amdgcn_permlane32_swap(W[1], W[3], false, false); a0.u[1] = r[0]; a0.u[3] = r[1];
  r = __builtin_amdgcn_permlane32_swap(W[4], W[6], false, false); a1.u[0] = r[0]; a1.u[2] = r[1];
  r = __builtin_amdgcn_permlane32_swap(W[5], W[7], false, false); a1.u[1] = r[0]; a1.u[3] = r[1];
  A0 = a0.h; A1 = a1.h;
}

__global__ __launch_bounds__(256) void srht_kernel(
    const float* __restrict__ x, const float* __restrict__ rad,
    const int* __restrict__ perm, float* __restrict__ out) {
  __shared__ __align__(16) float lds[4096];
  const int row  = blockIdx.x;
  const int tid  = threadIdx.x;
  const int w    = tid >> 6;        // FWHT block
  const int lane = tid & 63;
  const int q    = lane & 31;       // matrix column owned by this lane
  const int hi   = lane >> 5;

  // ---- H32 B-fragments: B[k][n=q], k = 16t + 8*hi + jj. Bs = H/32. ----
  f16x8 B0, B1, Bs0, Bs1;
  {
    H8U4 b0, b1, bs0, bs1;
#pragma unroll
    for (int t = 0; t < 2; t++) {
#pragma unroll
      for (int m = 0; m < 4; m++) {
        int k0 = 16 * t + 8 * hi + 2 * m;
        unsigned int s0 = (unsigned)(__popc(k0 & q) & 1);
        unsigned int s1 = (unsigned)(__popc((k0 + 1) & q) & 1);
        unsigned int sm = (s0 << 15) | (s1 << 31);
        unsigned int w1 = 0x3C003C00u ^ sm;   // +-1.0 f16
        unsigned int ws = 0x28002800u ^ sm;   // +-2^-5 f16
        if (t == 0) { b0.u[m] = w1; bs0.u[m] = ws; }
        else        { b1.u[m] = w1; bs1.u[m] = ws; }
      }
    }
    B0 = b0.h; B1 = b1.h; Bs0 = bs0.h; Bs1 = bs1.h;
  }

  // ---- first A = (x*rad0)^T : lane loads x[32k + q], k = 16t+8hi+jj ----
  f16x8 A0, A1;
  {
    const float* xp  = x + (size_t)row * 1024 + q;
    const float* r0p = rad + (w << 10) + q;
    H8U4 a0, a1;
#pragma unroll
    for (int t = 0; t < 2; t++) {
#pragma unroll
      for (int m = 0; m < 4; m++) {
        int k0 = ((t << 4) + (hi << 3) + (m << 1)) << 5;
        int k1 = k0 + 32;
        float v0 = xp[k0] * r0p[k0];
        float v1 = xp[k1] * r0p[k1];
        unsigned int wd = pkrtz(v0, v1);
        if (t == 0) a0.u[m] = wd; else a1.u[m] = wd;
      }
    }
    A0 = a0.h; A1 = a1.h;
  }

  f32x16 c;
  c = prod(A0, A1, B0, B1);                    // C1 = X^T H
  convA(c, A0, A1);
  c = prod(A0, A1, B0, B1);                    // C2 = H X H  (fwht #1)

  // ---- * rad1 (1/32 folded into Bs of next product) ----
  {
    const float* r1p = rad + ((4 + w) << 10) + q;
#pragma unroll
    for (int j = 0; j < 16; j++) {
      int p = (j & 3) + ((j >> 2) << 3) + (hi << 2);
      c[j] *= r1p[p << 5];
    }
  }
  convA(c, A0, A1);
  c = prod(A0, A1, Bs0, Bs1);                  // C3 (carries 1/32)
  convA(c, A0, A1);
  c = prod(A0, A1, B0, B1);                    // C4 = fwht #2 / 32

  // ---- * rad2 ----
  {
    const float* r2p = rad + ((8 + w) << 10) + q;
#pragma unroll
    for (int j = 0; j < 16; j++) {
      int p = (j & 3) + ((j >> 2) << 3) + (hi << 2);
      c[j] *= r2p[p << 5];
    }
  }
  convA(c, A0, A1);
  c = prod(A0, A1, Bs0, Bs1);                  // C5 (carries 1/32)
  convA(c, A0, A1);
  c = prod(A0, A1, B0, B1);                    // C6 = final h, i = 32p + q

  // ---- h -> LDS at true index (writes are 2-way/bank = free) ----
#pragma unroll
  for (int j = 0; j < 16; j++) {
    int p = (j & 3) + ((j >> 2) << 3) + (hi << 2);
    lds[(w << 10) + (p << 5) + q] = c[j];
  }
  __syncthreads();

  // ---- permutation gather: j = g*1024 + tid*4 -> fully coalesced
  //      perm loads (int4) and out stores (float4, 1KB/wave/instr) ----
  {
    float* orow = out + (size_t)row * 4096;
#pragma unroll
    for (int g = 0; g < 4; g++) {
      int j = (g << 10) + (tid << 2);
      int4 pi = *(const int4*)(perm + j);
      float4 o;
      o.x = lds[pi.x];
      o.y = lds[pi.y];
      o.z = lds[pi.z];
      o.w = lds[pi.w];
      *(float4*)(orow + j) = o;
    }
  }
}

extern "C" void kernel_launch(void* const* d_in, const int* in_sizes, int n_in,
                              void* d_out, int out_size, void* d_ws, size_t ws_size,
                              hipStream_t stream) {
  (void)n_in; (void)d_ws; (void)ws_size; (void)out_size;
  const float* x    = (const float*)d_in[0];
  const float* rad  = (const float*)d_in[1];
  const int*   perm = (const int*)d_in[2];
  float*       out  = (float*)d_out;
  const int rows = in_sizes[0] / 1024;  // 16384
  srht_kernel<<<rows, 256, 0, stream>>>(x, rad, perm, out);
}